// Round 4
// baseline (59.881 us; speedup 1.0000x reference)
//
#include <hip/hip_runtime.h>

// Sobel-like 4-kernel depthwise edge detector + sigmoid>0.5 threshold.
// Output[p] = (|e0|+|e1|+|e2|+|e3| > 0) ? 1.0f : 0.0f, with zero padding.
//
// x: (32,3,512,512) f32 -> 96 independent 512x512 images.
// One wave (64 lanes) owns a full 512-px-wide, 4-row-tall strip:
//   lane i covers pixels [i*8, i*8+8) of each row.
// Horizontal halos come from neighbor lanes via __shfl (wave edges are the
// image boundary -> zero pad), so NO scalar edge loads: 12 dwordx4 loads +
// 8 dwordx4 stores per thread for a 4x8 output tile.

#define IMG_H 512
#define IMG_W 512

typedef float f32x4 __attribute__((ext_vector_type(4)));

__global__ __launch_bounds__(256) void sobel_thresh_kernel(
    const float* __restrict__ x, float* __restrict__ out) {
    int t    = blockIdx.x * blockDim.x + threadIdx.x;
    int lane = t & 63;
    int wid  = t >> 6;        // 0..12287 : one wave per (img, 4-row group)
    int hg   = wid & 127;
    int img  = wid >> 7;
    int h0   = hg << 2;
    int w0   = lane << 3;

    const float* base = x + (size_t)img * (IMG_H * IMG_W);

    // ra[r][0] = left halo, ra[r][1..8] = 8 owned pixels, ra[r][9] = right halo
    float ra[6][10];
#pragma unroll
    for (int r = 0; r < 6; ++r) {
        int h = h0 - 1 + r;             // wave-uniform branch
        if (h >= 0 && h < IMG_H) {
            const float* rp = base + h * IMG_W + w0;
            f32x4 v0 = *reinterpret_cast<const f32x4*>(rp);
            f32x4 v1 = *reinterpret_cast<const f32x4*>(rp + 4);
            ra[r][1] = v0.x; ra[r][2] = v0.y; ra[r][3] = v0.z; ra[r][4] = v0.w;
            ra[r][5] = v1.x; ra[r][6] = v1.y; ra[r][7] = v1.z; ra[r][8] = v1.w;
            float lh = __shfl_up(v1.w, 1);   // lane i-1's pixel i*8-1
            float rh = __shfl_down(v0.x, 1); // lane i+1's pixel i*8+8
            ra[r][0] = (lane == 0)  ? 0.0f : lh;
            ra[r][9] = (lane == 63) ? 0.0f : rh;
        } else {
#pragma unroll
            for (int i = 0; i < 10; ++i) ra[r][i] = 0.0f;
        }
    }

    float* obase = out + (size_t)img * (IMG_H * IMG_W) + (size_t)h0 * IMG_W + w0;
#pragma unroll
    for (int i = 0; i < 4; ++i) {
        float res[8];
#pragma unroll
        for (int j = 0; j < 8; ++j) {
            float t0 = ra[i][j],     t1 = ra[i][j + 1],     t2 = ra[i][j + 2];
            float m0 = ra[i + 1][j],                        m2 = ra[i + 1][j + 2];
            float b0 = ra[i + 2][j], b1 = ra[i + 2][j + 1], b2 = ra[i + 2][j + 2];
            // k0 = [[-1,0,1],[-2,0,2],[-1,0,1]]
            float e0 = (t2 - t0) + 2.0f * (m2 - m0) + (b2 - b0);
            // k1 = [[1,2,1],[0,0,0],[-1,-2,-1]]
            float e1 = (t0 + 2.0f * t1 + t2) - (b0 + 2.0f * b1 + b2);
            // k2 = [[2,1,0],[1,0,-1],[0,-1,-2]]
            float e2 = 2.0f * t0 + t1 + m0 - m2 - b1 - 2.0f * b2;
            // k3 = [[0,-1,-2],[1,0,-1],[2,1,0]]
            float e3 = -t1 - 2.0f * t2 + m0 - m2 + 2.0f * b0 + b1;
            float s = fabsf(e0) + fabsf(e1) + fabsf(e2) + fabsf(e3);
            res[j] = (s > 0.0f) ? 1.0f : 0.0f;
        }
        f32x4 o0, o1;
        o0.x = res[0]; o0.y = res[1]; o0.z = res[2]; o0.w = res[3];
        o1.x = res[4]; o1.y = res[5]; o1.z = res[6]; o1.w = res[7];
        float* op = obase + i * IMG_W;
        __builtin_nontemporal_store(o0, reinterpret_cast<f32x4*>(op));
        __builtin_nontemporal_store(o1, reinterpret_cast<f32x4*>(op + 4));
    }
}

extern "C" void kernel_launch(void* const* d_in, const int* in_sizes, int n_in,
                              void* d_out, int out_size, void* d_ws, size_t ws_size,
                              hipStream_t stream) {
    const float* x = (const float*)d_in[0];
    float* out = (float*)d_out;
    // 96 imgs * 128 row-groups = 12288 waves = 786,432 threads
    int total = 96 * 128 * 64;
    int block = 256;
    int grid = total / block;  // 3072 blocks
    sobel_thresh_kernel<<<grid, block, 0, stream>>>(x, out);
}

// Round 5
// 37.754 us; speedup vs baseline: 1.5861x; 1.5861x over previous
//
#include <hip/hip_runtime.h>

// Sobel-like 4-kernel depthwise edge detector + sigmoid>0.5 threshold.
// Output[p] = (|e0|+|e1|+|e2|+|e3| > 0) ? 1.0f : 0.0f, with zero padding.
//
// x: (32,3,512,512) f32 -> 96 independent 512x512 images.
// One wave owns a full 512-px row-strip, 4 output rows tall.
// Lane i owns TWO far-apart float4s per row: px [i*4,i*4+4) (half 0) and
// px [256+i*4, 256+i*4+4) (half 1) -> every load/store instruction is
// 64 lanes x 16 B fully contiguous (1024 B). Halos via __shfl only:
// neighbor lanes within a half + seam broadcast between halves.

#define IMG_H 512
#define IMG_W 512

typedef float f32x4 __attribute__((ext_vector_type(4)));

__global__ __launch_bounds__(256) void sobel_thresh_kernel(
    const float* __restrict__ x, float* __restrict__ out) {
    int t    = blockIdx.x * blockDim.x + threadIdx.x;
    int lane = t & 63;
    int wid  = t >> 6;        // one wave per (img, 4-row group)
    int hg   = wid & 127;
    int img  = wid >> 7;
    int h0   = hg << 2;
    int wA   = lane << 2;         // half-0 column offset
    int wB   = 256 + (lane << 2); // half-1 column offset

    const float* base = x + (size_t)img * (IMG_H * IMG_W);

    // [r][0]=left halo, [1..4]=owned px, [5]=right halo
    float A[6][6], B[6][6];
#pragma unroll
    for (int r = 0; r < 6; ++r) {
        int h = h0 - 1 + r;             // wave-uniform branch
        if (h >= 0 && h < IMG_H) {
            const float* rp = base + h * IMG_W;
            f32x4 a = *reinterpret_cast<const f32x4*>(rp + wA);
            f32x4 b = *reinterpret_cast<const f32x4*>(rp + wB);
            A[r][1] = a.x; A[r][2] = a.y; A[r][3] = a.z; A[r][4] = a.w;
            B[r][1] = b.x; B[r][2] = b.y; B[r][3] = b.z; B[r][4] = b.w;
            float a_l = __shfl_up(a.w, 1);    // lane-1's px i*4-1
            float a_r = __shfl_down(a.x, 1);  // lane+1's px i*4+4
            float b_l = __shfl_up(b.w, 1);
            float b_r = __shfl_down(b.x, 1);
            float seam_r = __shfl(b.x, 0);    // px 256 (right halo of px 255)
            float seam_l = __shfl(a.w, 63);   // px 255 (left halo of px 256)
            A[r][0] = (lane == 0)  ? 0.0f   : a_l;   // image left edge
            A[r][5] = (lane == 63) ? seam_r : a_r;   // seam
            B[r][0] = (lane == 0)  ? seam_l : b_l;   // seam
            B[r][5] = (lane == 63) ? 0.0f   : b_r;   // image right edge
        } else {
#pragma unroll
            for (int i = 0; i < 6; ++i) { A[r][i] = 0.0f; B[r][i] = 0.0f; }
        }
    }

    float* obase = out + (size_t)img * (IMG_H * IMG_W) + (size_t)h0 * IMG_W;
#pragma unroll
    for (int i = 0; i < 4; ++i) {
        f32x4 oA, oB;
#pragma unroll
        for (int half = 0; half < 2; ++half) {
            const float (*ra)[6] = half ? B : A;
            f32x4* o = half ? &oB : &oA;
#pragma unroll
            for (int j = 0; j < 4; ++j) {
                float t0 = ra[i][j],     t1 = ra[i][j + 1],     t2 = ra[i][j + 2];
                float m0 = ra[i + 1][j],                        m2 = ra[i + 1][j + 2];
                float b0 = ra[i + 2][j], b1 = ra[i + 2][j + 1], b2 = ra[i + 2][j + 2];
                // k0 = [[-1,0,1],[-2,0,2],[-1,0,1]]
                float e0 = (t2 - t0) + 2.0f * (m2 - m0) + (b2 - b0);
                // k1 = [[1,2,1],[0,0,0],[-1,-2,-1]]
                float e1 = (t0 + 2.0f * t1 + t2) - (b0 + 2.0f * b1 + b2);
                // k2 = [[2,1,0],[1,0,-1],[0,-1,-2]]
                float e2 = 2.0f * t0 + t1 + m0 - m2 - b1 - 2.0f * b2;
                // k3 = [[0,-1,-2],[1,0,-1],[2,1,0]]
                float e3 = -t1 - 2.0f * t2 + m0 - m2 + 2.0f * b0 + b1;
                float s = fabsf(e0) + fabsf(e1) + fabsf(e2) + fabsf(e3);
                (*o)[j] = (s > 0.0f) ? 1.0f : 0.0f;
            }
        }
        float* op = obase + i * IMG_W;
        __builtin_nontemporal_store(oA, reinterpret_cast<f32x4*>(op + wA));
        __builtin_nontemporal_store(oB, reinterpret_cast<f32x4*>(op + wB));
    }
}

extern "C" void kernel_launch(void* const* d_in, const int* in_sizes, int n_in,
                              void* d_out, int out_size, void* d_ws, size_t ws_size,
                              hipStream_t stream) {
    const float* x = (const float*)d_in[0];
    float* out = (float*)d_out;
    // 96 imgs * 128 row-groups = 12288 waves = 786,432 threads
    int total = 96 * 128 * 64;
    int block = 256;
    int grid = total / block;  // 3072 blocks
    sobel_thresh_kernel<<<grid, block, 0, stream>>>(x, out);
}